// Round 14
// baseline (378.053 us; speedup 1.0000x reference)
//
#include <hip/hip_runtime.h>

#define N_NODES 100000
#define N_EDGES 1600000
#define NBUCK 196                 // ceil(100000 / 512)
#define CAP_BIN 64                // LDS bin depth in k_bin
#define CAP_B 12288               // per-bucket src staging in k_bucket (mean 8163)
#define CVT_BLKS 12500            // N*128/4 / 256
// D_IN=128, D_HID=256, D_OUT=128

typedef float v4f __attribute__((ext_vector_type(4)));
typedef __bf16 v8bf __attribute__((ext_vector_type(8)));
typedef __bf16 v4bf __attribute__((ext_vector_type(4)));
typedef unsigned int v4u __attribute__((ext_vector_type(4)));

union FragU { v4u u; v8bf b; };
union PkU { unsigned int u; __bf16 h[2]; };
union Pk2 { uint2 u2; __bf16 h[4]; };

__device__ __forceinline__ int clampN(int v) {
    return v < 0 ? 0 : (v >= N_NODES ? N_NODES - 1 : v);
}
__device__ __forceinline__ float bfhi(unsigned int u) { return __uint_as_float(u & 0xffff0000u); }
__device__ __forceinline__ float bflo(unsigned int u) { return __uint_as_float(u << 16); }

// async global->LDS, 16B per lane; LDS dest must be base+lane*16 (linear)
__device__ __forceinline__ void gll16(const void* g, void* l) {
    __builtin_amdgcn_global_load_lds(
        (const __attribute__((address_space(1))) unsigned int*)g,
        (__attribute__((address_space(3))) unsigned int*)l, 16, 0, 0);
}

// ---------------- fused prep: cvt_x | 4x pack_w | bucket count ----------------
__global__ __launch_bounds__(256) void k_prep(
    const float* __restrict__ x, __bf16* __restrict__ a2,
    const float* __restrict__ Wl1, const float* __restrict__ Wr1,
    const float* __restrict__ Wl2, const float* __restrict__ Wr2,
    __bf16* __restrict__ Wl1p, __bf16* __restrict__ Wr1p,
    __bf16* __restrict__ Wl2p, __bf16* __restrict__ Wr2p,
    const int* __restrict__ dst, int* __restrict__ bucketCnt)
{
    const int b = blockIdx.x, tid = threadIdx.x;
    if (b < CVT_BLKS) {
        int t = b * 256 + tid;
        float4 v = ((const float4*)x)[t];
        int row = t >> 5, c4 = t & 31;
        v4bf o = { (__bf16)v.x, (__bf16)v.y, (__bf16)v.z, (__bf16)v.w };
        *(v4bf*)(a2 + (size_t)row * 256 + 128 + c4 * 4) = o;
    } else if (b < CVT_BLKS + 64) {
        int pb = b - CVT_BLKS;
        int which = pb >> 4;
        int t = (pb & 15) * 256 + tid;
        const float* W = which == 0 ? Wl1 : which == 1 ? Wr1 : which == 2 ? Wl2 : Wr2;
        __bf16* Wp     = which == 0 ? Wl1p : which == 1 ? Wr1p : which == 2 ? Wl2p : Wr2p;
        const int N = (which < 2) ? 256 : 128;
        const int NT = N >> 4;
        int l = t & 63;
        int fi = t >> 6;
        int kc = fi / NT, nt = fi % NT;
        int k0 = kc * 32 + (l >> 4) * 8;
        int col = nt * 16 + (l & 15);
        v8bf o;
        #pragma unroll
        for (int j = 0; j < 8; ++j) o[j] = (__bf16)W[(size_t)(k0 + j) * N + col];
        *(v8bf*)(Wp + (size_t)t * 8) = o;
    } else {
        __shared__ int h[NBUCK];
        for (int i = tid; i < NBUCK; i += 256) h[i] = 0;
        __syncthreads();
        int cb = b - CVT_BLKS - 64;
        int e0 = cb * 4096;
        int e1 = e0 + 4096; if (e1 > N_EDGES) e1 = N_EDGES;
        for (int e = e0 + tid; e < e1; e += 256)
            atomicAdd(&h[clampN(dst[e]) >> 9], 1);
        __syncthreads();
        for (int i = tid; i < NBUCK; i += 256)
            if (h[i]) atomicAdd(&bucketCnt[i], h[i]);
    }
}

// ---------------- CSR build: bucketed counting sort ----------------
__global__ __launch_bounds__(256) void k_scanb(
    const int* __restrict__ bucketCnt, int* __restrict__ baseB,
    int* __restrict__ gcur, int* __restrict__ rowp)
{
    const int t = threadIdx.x;
    int v = (t < NBUCK) ? bucketCnt[t] : 0;
    int incl = v;
    #pragma unroll
    for (int off = 1; off < 64; off <<= 1) {
        int u = __shfl_up(incl, off);
        if ((t & 63) >= off) incl += u;
    }
    __shared__ int wt[4];
    if ((t & 63) == 63) wt[t >> 6] = incl;
    __syncthreads();
    int woff = 0;
    #pragma unroll
    for (int k = 0; k < 4; ++k) if (k < (t >> 6)) woff += wt[k];
    int excl = woff + incl - v;
    if (t < NBUCK) { baseB[t] = excl; gcur[t] = excl; }
    if (t == NBUCK) { baseB[NBUCK] = excl; rowp[N_NODES] = excl; }
}

__global__ __launch_bounds__(256) void k_bin(
    const int* __restrict__ src, const int* __restrict__ dst,
    int* __restrict__ gcur, unsigned int* __restrict__ packed)
{
    __shared__ unsigned int bins[256 * CAP_BIN];   // 64 KB
    __shared__ int cnt[256];
    const int tid = threadIdx.x;
    cnt[tid] = 0;
    __syncthreads();
    const int epb = (N_EDGES + gridDim.x - 1) / gridDim.x;
    int e0 = blockIdx.x * epb;
    int e1 = e0 + epb; if (e1 > N_EDGES) e1 = N_EDGES;
    for (int ch = e0; ch < e1; ch += 4096) {
        int chEnd = ch + 4096; if (chEnd > e1) chEnd = e1;
        for (int e = ch + tid; e < chEnd; e += 256) {
            int s = clampN(src[e]);
            int d = clampN(dst[e]);
            unsigned int val = (unsigned int)s | ((unsigned int)(d & 511) << 17);
            int b = d >> 9;
            int slot = atomicAdd(&cnt[b], 1);
            if (slot < CAP_BIN) bins[b * CAP_BIN + slot] = val;
            else {
                int g = atomicAdd(&gcur[b], 1);
                packed[g] = val;
            }
        }
        __syncthreads();
        int n = cnt[tid]; if (n > CAP_BIN) n = CAP_BIN;
        if (tid < NBUCK && n > 0) {
            int g = atomicAdd(&gcur[tid], n);
            for (int j = 0; j < n; ++j) packed[g + j] = bins[tid * CAP_BIN + j];
        }
        __syncthreads();
        cnt[tid] = 0;
        __syncthreads();
    }
}

__global__ __launch_bounds__(256) void k_bucket(
    const int* __restrict__ baseB, const unsigned int* __restrict__ packed,
    int* __restrict__ rowp, int* __restrict__ edge_src)
{
    __shared__ int hist[512], cur[512];
    __shared__ int wt[4];
    __shared__ unsigned int buf[CAP_B];            // 48 KB
    const int b = blockIdx.x, tid = threadIdx.x;
    const int lo = baseB[b], hi = baseB[b + 1], c = hi - lo;
    for (int i = tid; i < 512; i += 256) hist[i] = 0;
    __syncthreads();
    for (int e = tid; e < c; e += 256)
        atomicAdd(&hist[packed[lo + e] >> 17], 1);
    __syncthreads();
    int a0 = hist[2 * tid], a1 = hist[2 * tid + 1];
    int s = a0 + a1;
    int incl = s;
    #pragma unroll
    for (int off = 1; off < 64; off <<= 1) {
        int u = __shfl_up(incl, off);
        if ((tid & 63) >= off) incl += u;
    }
    if ((tid & 63) == 63) wt[tid >> 6] = incl;
    __syncthreads();
    int woff = 0;
    #pragma unroll
    for (int k = 0; k < 4; ++k) if (k < (tid >> 6)) woff += wt[k];
    int ep = woff + incl - s;
    cur[2 * tid] = ep;
    cur[2 * tid + 1] = ep + a0;
    int n0 = b * 512 + 2 * tid;
    if (n0 < N_NODES)     rowp[n0]     = lo + ep;
    if (n0 + 1 < N_NODES) rowp[n0 + 1] = lo + ep + a0;
    __syncthreads();
    for (int e = tid; e < c; e += 256) {
        unsigned int v = packed[lo + e];
        int dl = v >> 17;
        unsigned int sv = v & 0x1FFFFu;
        int pos = atomicAdd(&cur[dl], 1);
        if (pos < CAP_B) buf[pos] = sv;
        else edge_src[lo + pos] = (int)sv;
    }
    __syncthreads();
    int cc = c < CAP_B ? c : CAP_B;
    for (int e = tid; e < cc; e += 256) edge_src[lo + e] = (int)buf[e];
}

// ---------------- CSR mean-gather (layer 2 only): one wave per node ----------------
__global__ __launch_bounds__(256) void k_gather2(
    const int* __restrict__ rp, const int* __restrict__ es,
    const __bf16* __restrict__ tab, float* __restrict__ outp)
{
    int wid = (blockIdx.x * 256 + threadIdx.x) >> 6;
    int l = threadIdx.x & 63;
    if (wid >= N_NODES) return;
    int start = rp[wid], end = rp[wid + 1];
    const int slot = l >> 4, c = l & 15;
    const size_t coff = (size_t)(c * 8);
    float s0 = 0.f, s1 = 0.f, s2 = 0.f, s3 = 0.f;
    float s4 = 0.f, s5 = 0.f, s6 = 0.f, s7 = 0.f;

    int e0 = start + slot;
    int e1 = e0 + 4;
    int e2 = e1 + 4;
    bool h0 = e0 < end, h1 = e1 < end, h2 = e2 < end;
    v4u r0 = {0, 0, 0, 0}, r1 = {0, 0, 0, 0};
    if (h0) r0 = *(const v4u*)(tab + (size_t)es[e0] * 256 + coff);
    if (h1) r1 = *(const v4u*)(tab + (size_t)es[e1] * 256 + coff);
    int i2 = h2 ? es[e2] : 0;

    while (h0) {
        v4u r2 = {0, 0, 0, 0};
        if (h2) r2 = *(const v4u*)(tab + (size_t)i2 * 256 + coff);
        int e3 = e2 + 4;
        bool h3 = e3 < end;
        int i3 = h3 ? es[e3] : 0;
        s0 += bflo(r0.x); s1 += bfhi(r0.x);
        s2 += bflo(r0.y); s3 += bfhi(r0.y);
        s4 += bflo(r0.z); s5 += bfhi(r0.z);
        s6 += bflo(r0.w); s7 += bfhi(r0.w);
        r0 = r1; r1 = r2;
        h0 = h1; h1 = h2; h2 = h3;
        i2 = i3; e2 = e3;
    }

    s0 += __shfl_xor(s0, 16); s1 += __shfl_xor(s1, 16);
    s2 += __shfl_xor(s2, 16); s3 += __shfl_xor(s3, 16);
    s4 += __shfl_xor(s4, 16); s5 += __shfl_xor(s5, 16);
    s6 += __shfl_xor(s6, 16); s7 += __shfl_xor(s7, 16);
    s0 += __shfl_xor(s0, 32); s1 += __shfl_xor(s1, 32);
    s2 += __shfl_xor(s2, 32); s3 += __shfl_xor(s3, 32);
    s4 += __shfl_xor(s4, 32); s5 += __shfl_xor(s5, 32);
    s6 += __shfl_xor(s6, 32); s7 += __shfl_xor(s7, 32);
    float invd = 1.f / fmaxf((float)(end - start), 1.f);
    if (slot == 0) {
        // own partial (h@Wr2 + bl2 + p2, bf16) + gathered mean -> f32 out
        v4u pu = *(const v4u*)(tab + (size_t)wid * 256 + 128 + c * 8);
        float4 va, vb;
        va.x = s0 * invd + bflo(pu.x); va.y = s1 * invd + bfhi(pu.x);
        va.z = s2 * invd + bflo(pu.y); va.w = s3 * invd + bfhi(pu.y);
        vb.x = s4 * invd + bflo(pu.z); vb.y = s5 * invd + bfhi(pu.z);
        vb.z = s6 * invd + bflo(pu.w); vb.w = s7 * invd + bfhi(pu.w);
        ((float4*)outp)[(size_t)wid * 32 + c * 2]     = va;
        ((float4*)outp)[(size_t)wid * 32 + c * 2 + 1] = vb;
    }
}

// ---------------- fused gather + layer-1 GEMM ----------------
// Per 32-row tile: 8 waves gather their 4 rows' neighbor means (random reads of
// a2 x-halves) -> ds_write bf16 means into swizzled aAgg; meanwhile
// global_load_lds streams this tile's x-half (aX, inverse-swizzled source) and
// p1 (pS) under the gather. One barrier, then MFMA + coalesced epilogue.
__global__ __launch_bounds__(512, 2) void k_gws1g(
    const __bf16* __restrict__ a2,
    const int* __restrict__ rowp, const int* __restrict__ es,
    const __bf16* __restrict__ WpA, const __bf16* __restrict__ WpB,
    const float* __restrict__ bias, const float* __restrict__ pert,
    __bf16* __restrict__ outb, int ntiles)
{
    __shared__ char aAgg[8192];
    __shared__ char aX[8192];
    __shared__ char hS[16384];
    __shared__ char pS[32768];
    const int tid = threadIdx.x;
    const int w = tid >> 6, l = tid & 63;
    const int lrow = l & 15, kg = l >> 4;
    const v4f zf = {0.f, 0.f, 0.f, 0.f};

    // resident B panel: B' = [Wl1 ; Wr1] K-concat, NT=16
    FragU bw[8][2];
    #pragma unroll
    for (int kc = 0; kc < 8; ++kc)
        #pragma unroll
        for (int nt = 0; nt < 2; ++nt) {
            const __bf16* Wp = (kc < 4) ? WpA : WpB;
            int fi = (kc & 3) * 16 + w * 2 + nt;
            bw[kc][nt].u = *(const v4u*)(Wp + ((size_t)fi * 64 + l) * 8);
        }

    const int slot = l >> 4, c = l & 15;

    for (int tile = blockIdx.x; tile < ntiles; tile += gridDim.x) {
        const int row0 = tile * 32;
        // issue async staging: x-half of this tile + pert of this tile
        {
            int row = tid >> 4, ci = tid & 15;          // 512 chunks = 32 x 16
            int sc = ci ^ (row & 7);
            gll16(a2 + (size_t)(row0 + row) * 256 + 128 + sc * 8, aX + tid * 16);
        }
        #pragma unroll
        for (int k2 = 0; k2 < 4; ++k2) {
            int ch = k2 * 512 + tid;                    // 2048 = 32 rows x 64 x 16B
            int row = ch >> 6, c16 = ch & 63;
            gll16(pert + (size_t)(row0 + row) * 256 + c16 * 4, pS + ch * 16);
        }

        // gather this wave's 4 rows (means -> aAgg, swizzled)
        #pragma unroll
        for (int j = 0; j < 4; ++j) {
            const int row = w * 4 + j;
            const int grow = row0 + row;
            int start = rowp[grow], end = rowp[grow + 1];
            float s0 = 0.f, s1 = 0.f, s2 = 0.f, s3 = 0.f;
            float s4 = 0.f, s5 = 0.f, s6 = 0.f, s7 = 0.f;
            int e0 = start + slot;
            int e1 = e0 + 4;
            int e2 = e1 + 4;
            bool h0 = e0 < end, h1 = e1 < end, h2 = e2 < end;
            v4u r0 = {0, 0, 0, 0}, r1 = {0, 0, 0, 0};
            if (h0) r0 = *(const v4u*)(a2 + (size_t)es[e0] * 256 + 128 + c * 8);
            if (h1) r1 = *(const v4u*)(a2 + (size_t)es[e1] * 256 + 128 + c * 8);
            int i2 = h2 ? es[e2] : 0;
            while (h0) {
                v4u r2 = {0, 0, 0, 0};
                if (h2) r2 = *(const v4u*)(a2 + (size_t)i2 * 256 + 128 + c * 8);
                int e3 = e2 + 4;
                bool h3 = e3 < end;
                int i3 = h3 ? es[e3] : 0;
                s0 += bflo(r0.x); s1 += bfhi(r0.x);
                s2 += bflo(r0.y); s3 += bfhi(r0.y);
                s4 += bflo(r0.z); s5 += bfhi(r0.z);
                s6 += bflo(r0.w); s7 += bfhi(r0.w);
                r0 = r1; r1 = r2;
                h0 = h1; h1 = h2; h2 = h3;
                i2 = i3; e2 = e3;
            }
            s0 += __shfl_xor(s0, 16); s1 += __shfl_xor(s1, 16);
            s2 += __shfl_xor(s2, 16); s3 += __shfl_xor(s3, 16);
            s4 += __shfl_xor(s4, 16); s5 += __shfl_xor(s5, 16);
            s6 += __shfl_xor(s6, 16); s7 += __shfl_xor(s7, 16);
            s0 += __shfl_xor(s0, 32); s1 += __shfl_xor(s1, 32);
            s2 += __shfl_xor(s2, 32); s3 += __shfl_xor(s3, 32);
            s4 += __shfl_xor(s4, 32); s5 += __shfl_xor(s5, 32);
            s6 += __shfl_xor(s6, 32); s7 += __shfl_xor(s7, 32);
            float invd = 1.f / fmaxf((float)(end - start), 1.f);
            if (slot == 0) {
                PkU pa, pb, pc, pd;
                pa.h[0] = (__bf16)(s0 * invd); pa.h[1] = (__bf16)(s1 * invd);
                pb.h[0] = (__bf16)(s2 * invd); pb.h[1] = (__bf16)(s3 * invd);
                pc.h[0] = (__bf16)(s4 * invd); pc.h[1] = (__bf16)(s5 * invd);
                pd.h[0] = (__bf16)(s6 * invd); pd.h[1] = (__bf16)(s7 * invd);
                v4u o = { pa.u, pb.u, pc.u, pd.u };
                int byte = row * 256 + ((c * 16) ^ ((row & 7) << 4));
                *(v4u*)(aAgg + byte) = o;
            }
        }
        __syncthreads();   // drains glls + gather ds_writes visible

        // GEMM: kc 0-3 from aAgg, kc 4-7 from aX (256B rows, same XOR swizzle)
        #pragma unroll
        for (int rf = 0; rf < 2; ++rf) {
            const int arow = rf * 16 + lrow;
            FragU a[8];
            #pragma unroll
            for (int kc = 0; kc < 4; ++kc) {
                int byte = arow * 256 + ((kc * 64 + kg * 16) ^ ((arow & 7) << 4));
                a[kc].u = *(const v4u*)(aAgg + byte);
            }
            #pragma unroll
            for (int kc = 4; kc < 8; ++kc) {
                int byte = arow * 256 + (((kc - 4) * 64 + kg * 16) ^ ((arow & 7) << 4));
                a[kc].u = *(const v4u*)(aX + byte);
            }
            v4f acc[2] = {zf, zf};
            #pragma unroll
            for (int kc = 0; kc < 8; ++kc) {
                acc[0] = __builtin_amdgcn_mfma_f32_16x16x32_bf16(a[kc].b, bw[kc][0].b, acc[0], 0, 0, 0);
                acc[1] = __builtin_amdgcn_mfma_f32_16x16x32_bf16(a[kc].b, bw[kc][1].b, acc[1], 0, 0, 0);
            }
            #pragma unroll
            for (int nt = 0; nt < 2; ++nt)
                #pragma unroll
                for (int r = 0; r < 4; ++r) {
                    int row = rf * 16 + kg * 4 + r;
                    int col = w * 32 + nt * 16 + lrow;
                    int byte = (row * 512 + col * 2) ^ ((row & 7) << 4);
                    *(__bf16*)(hS + byte) = (__bf16)acc[nt][r];
                }
        }
        __syncthreads();   // hS visible

        // coalesced epilogue: h = acc + bl1 + p1 -> bf16 [N][256]
        #pragma unroll
        for (int it = 0; it < 4; ++it) {
            int chunk = it * 512 + tid;       // 2048 = 32 rows x 64 x 8B
            int row = chunk >> 6, c4 = chunk & 63;
            int grow = row0 + row;            // N % 32 == 0: never OOB
            int byte = (row * 512 + c4 * 8) ^ ((row & 7) << 4);
            Pk2 pk; pk.u2 = *(const uint2*)(hS + byte);
            float4 pv = *(const float4*)(pS + (row * 64 + c4) * 16);
            float4 bv = ((const float4*)bias)[c4];
            PkU o0, o1;
            o0.h[0] = (__bf16)((float)pk.h[0] + pv.x + bv.x);
            o0.h[1] = (__bf16)((float)pk.h[1] + pv.y + bv.y);
            o1.h[0] = (__bf16)((float)pk.h[2] + pv.z + bv.z);
            o1.h[1] = (__bf16)((float)pk.h[3] + pv.w + bv.w);
            uint2 ov = { o0.u, o1.u };
            *(uint2*)(outb + (size_t)grow * 256 + c4 * 4) = ov;
        }
        __syncthreads();   // protect aAgg/aX/hS/pS for next iteration
    }
}

// ---------------- layer-2 GEMM (R13 structure, unchanged) ----------------
__device__ __forceinline__ void stage_a32(
    const __bf16* __restrict__ A, int tile, int tid, char* buf)
{
    const int row0 = tile * 32;
    #pragma unroll
    for (int k = 0; k < 2; ++k) {
        int ch = k * 512 + tid;                 // 1024 = 32 rows x 32 x 16B
        int row = ch >> 5, c16 = ch & 31;
        int sc = c16 ^ (row & 7);
        gll16(A + (size_t)(row0 + row) * 256 + sc * 8, buf + ch * 16);
    }
}

__global__ __launch_bounds__(512, 2) void k_gws2(
    const __bf16* __restrict__ A,
    const __bf16* __restrict__ WpA, const __bf16* __restrict__ WpB,
    const float* __restrict__ bias, const float* __restrict__ pert,
    __bf16* __restrict__ outb, int ntiles)
{
    __shared__ char aS0[16384];
    __shared__ char aS1[16384];
    __shared__ char hS[16384];
    __shared__ char pS[16384];
    const int tid = threadIdx.x;
    const int w = tid >> 6, l = tid & 63;
    const int lrow = l & 15, kg = l >> 4;
    const v4f zf = {0.f, 0.f, 0.f, 0.f};

    // B'' = [Wl2 | Wr2] N-concat, NT=8
    FragU bw[8][2];
    #pragma unroll
    for (int kc = 0; kc < 8; ++kc)
        #pragma unroll
        for (int nt = 0; nt < 2; ++nt) {
            const __bf16* Wp = (w < 4) ? WpA : WpB;
            int fi = kc * 8 + (w & 3) * 2 + nt;
            bw[kc][nt].u = *(const v4u*)(Wp + ((size_t)fi * 64 + l) * 8);
        }

    int tile = blockIdx.x;
    int cur = 0;
    if (tile < ntiles) stage_a32(A, tile, tid, aS0);
    __syncthreads();

    for (; tile < ntiles; tile += gridDim.x) {
        {   // pert for THIS tile (p2: 128 f32/row)
            #pragma unroll
            for (int k = 0; k < 2; ++k) {
                int ch = k * 512 + tid;
                int row = ch >> 5, c16 = ch & 31;
                gll16(pert + (size_t)(tile * 32 + row) * 128 + c16 * 4, pS + ch * 16);
            }
        }
        int nxt = tile + (int)gridDim.x;
        if (nxt < ntiles) stage_a32(A, nxt, tid, cur ? aS0 : aS1);
        const char* aSc = cur ? aS1 : aS0;

        const int row0 = tile * 32;
        #pragma unroll
        for (int rf = 0; rf < 2; ++rf) {
            const int arow = rf * 16 + lrow;
            FragU a[8];
            #pragma unroll
            for (int kc = 0; kc < 8; ++kc) {
                int byte = arow * 512 + ((kc * 64 + kg * 16) ^ ((arow & 7) << 4));
                a[kc].u = *(const v4u*)(aSc + byte);
            }
            v4f acc[2] = {zf, zf};
            #pragma unroll
            for (int kc = 0; kc < 8; ++kc) {
                acc[0] = __builtin_amdgcn_mfma_f32_16x16x32_bf16(a[kc].b, bw[kc][0].b, acc[0], 0, 0, 0);
                acc[1] = __builtin_amdgcn_mfma_f32_16x16x32_bf16(a[kc].b, bw[kc][1].b, acc[1], 0, 0, 0);
            }
            #pragma unroll
            for (int nt = 0; nt < 2; ++nt)
                #pragma unroll
                for (int r = 0; r < 4; ++r) {
                    int row = rf * 16 + kg * 4 + r;
                    int col = w * 32 + nt * 16 + lrow;
                    int byte = (row * 512 + col * 2) ^ ((row & 7) << 4);
                    *(__bf16*)(hS + byte) = (__bf16)acc[nt][r];
                }
        }
        __syncthreads();

        #pragma unroll
        for (int it = 0; it < 4; ++it) {
            int chunk = it * 512 + tid;
            int row = chunk >> 6, c4 = chunk & 63;
            int grow = row0 + row;
            int byte = (row * 512 + c4 * 8) ^ ((row & 7) << 4);
            Pk2 pk; pk.u2 = *(const uint2*)(hS + byte);
            uint2 ov;
            if (c4 < 32) {
                ov = pk.u2;                   // raw t2 half
            } else {
                float4 pv = *(const float4*)(pS + (row * 32 + (c4 - 32)) * 16);
                float4 bv = ((const float4*)bias)[c4 - 32];
                PkU o0, o1;
                o0.h[0] = (__bf16)((float)pk.h[0] + pv.x + bv.x);
                o0.h[1] = (__bf16)((float)pk.h[1] + pv.y + bv.y);
                o1.h[0] = (__bf16)((float)pk.h[2] + pv.z + bv.z);
                o1.h[1] = (__bf16)((float)pk.h[3] + pv.w + bv.w);
                ov.x = o0.u; ov.y = o1.u;
            }
            *(uint2*)(outb + (size_t)grow * 256 + c4 * 4) = ov;
        }
        __syncthreads();
        cur ^= 1;
    }
}

extern "C" void kernel_launch(void* const* d_in, const int* in_sizes, int n_in,
                              void* d_out, int out_size, void* d_ws, size_t ws_size,
                              hipStream_t stream)
{
    const float* x   = (const float*)d_in[0];
    const int*   ei  = (const int*)d_in[1];
    const float* p1  = (const float*)d_in[2];
    const float* p2  = (const float*)d_in[3];
    const float* Wl1 = (const float*)d_in[4];
    const float* bl1 = (const float*)d_in[5];
    const float* Wr1 = (const float*)d_in[6];
    const float* Wl2 = (const float*)d_in[7];
    const float* bl2 = (const float*)d_in[8];
    const float* Wr2 = (const float*)d_in[9];
    const int* src = ei;
    const int* dst = ei + N_EDGES;

    const size_t NPAD = (size_t)N_NODES + 64;
    char* wp = (char*)d_ws;
    __bf16* a2   = (__bf16*)wp; wp += NPAD * 256 * 2;   // A': x in second half
    __bf16* hb   = (__bf16*)wp; wp += NPAD * 256 * 2;   // h
    __bf16* u2b  = (__bf16*)wp; wp += NPAD * 256 * 2;   // [t2 | partial]
    __bf16* Wl1p = (__bf16*)wp; wp += 128 * 256 * 2;
    __bf16* Wr1p = (__bf16*)wp; wp += 128 * 256 * 2;
    __bf16* Wl2p = (__bf16*)wp; wp += 256 * 128 * 2;
    __bf16* Wr2p = (__bf16*)wp; wp += 256 * 128 * 2;
    int* bucketCnt = (int*)wp; wp += 512 * 4;
    int* baseB     = (int*)wp; wp += 512 * 4;
    int* gcur      = (int*)wp; wp += 512 * 4;
    int* rowp      = (int*)wp; wp += (size_t)(N_NODES + 1) * 4 + 12;
    unsigned int* packed = (unsigned int*)wp; wp += (size_t)N_EDGES * 4;
    int* es        = (int*)wp;

    hipMemsetAsync(bucketCnt, 0, 512 * 4, stream);

    const int gblocks = (N_NODES * 64 + 255) / 256;
    const int tiles32 = N_NODES / 32;                   // 3125 exact
    const int prep_blocks = CVT_BLKS + 64 + (N_EDGES + 4095) / 4096;  // 12955

    k_prep<<<prep_blocks, 256, 0, stream>>>(
        x, a2, Wl1, Wr1, Wl2, Wr2, Wl1p, Wr1p, Wl2p, Wr2p, dst, bucketCnt);
    k_scanb<<<1, 256, 0, stream>>>(bucketCnt, baseB, gcur, rowp);
    k_bin<<<256, 256, 0, stream>>>(src, dst, gcur, packed);
    k_bucket<<<NBUCK, 256, 0, stream>>>(baseB, packed, rowp, es);

    k_gws1g<<<512, 512, 0, stream>>>(a2, rowp, es, Wl1p, Wr1p, bl1, p1, hb, tiles32);
    k_gws2<<<512, 512, 0, stream>>>(hb, Wl2p, Wr2p, bl2, p2, u2b, tiles32);
    k_gather2<<<gblocks, 256, 0, stream>>>(rowp, es, u2b, (float*)d_out);
}

// Round 15
// 289.101 us; speedup vs baseline: 1.3077x; 1.3077x over previous
//
#include <hip/hip_runtime.h>

#define N_NODES 100000
#define N_EDGES 1600000
#define NBUCK 196                 // ceil(100000 / 512)
#define CAP_BIN 64                // LDS bin depth in k_bin
#define CAP_B 12288               // per-bucket src staging in k_bucket (mean 8163)
#define CVT_BLKS 12500            // N*128/4 / 256
// D_IN=128, D_HID=256, D_OUT=128

typedef float v4f __attribute__((ext_vector_type(4)));
typedef __bf16 v8bf __attribute__((ext_vector_type(8)));
typedef __bf16 v4bf __attribute__((ext_vector_type(4)));
typedef unsigned int v4u __attribute__((ext_vector_type(4)));

union FragU { v4u u; v8bf b; };
union PkU { unsigned int u; __bf16 h[2]; };
union Pk2 { uint2 u2; __bf16 h[4]; };

__device__ __forceinline__ int clampN(int v) {
    return v < 0 ? 0 : (v >= N_NODES ? N_NODES - 1 : v);
}
__device__ __forceinline__ float bfhi(unsigned int u) { return __uint_as_float(u & 0xffff0000u); }
__device__ __forceinline__ float bflo(unsigned int u) { return __uint_as_float(u << 16); }

// async global->LDS, 16B per lane; LDS dest must be base+lane*16 (linear)
__device__ __forceinline__ void gll16(const void* g, void* l) {
    __builtin_amdgcn_global_load_lds(
        (const __attribute__((address_space(1))) unsigned int*)g,
        (__attribute__((address_space(3))) unsigned int*)l, 16, 0, 0);
}

// ---------------- fused prep: cvt_x | 4x pack_w | bucket count ----------------
__global__ __launch_bounds__(256) void k_prep(
    const float* __restrict__ x, __bf16* __restrict__ a2,
    const float* __restrict__ Wl1, const float* __restrict__ Wr1,
    const float* __restrict__ Wl2, const float* __restrict__ Wr2,
    __bf16* __restrict__ Wl1p, __bf16* __restrict__ Wr1p,
    __bf16* __restrict__ Wl2p, __bf16* __restrict__ Wr2p,
    const int* __restrict__ dst, int* __restrict__ bucketCnt)
{
    const int b = blockIdx.x, tid = threadIdx.x;
    if (b < CVT_BLKS) {
        int t = b * 256 + tid;
        float4 v = ((const float4*)x)[t];
        int row = t >> 5, c4 = t & 31;
        v4bf o = { (__bf16)v.x, (__bf16)v.y, (__bf16)v.z, (__bf16)v.w };
        *(v4bf*)(a2 + (size_t)row * 256 + 128 + c4 * 4) = o;
    } else if (b < CVT_BLKS + 64) {
        int pb = b - CVT_BLKS;
        int which = pb >> 4;
        int t = (pb & 15) * 256 + tid;
        const float* W = which == 0 ? Wl1 : which == 1 ? Wr1 : which == 2 ? Wl2 : Wr2;
        __bf16* Wp     = which == 0 ? Wl1p : which == 1 ? Wr1p : which == 2 ? Wl2p : Wr2p;
        const int N = (which < 2) ? 256 : 128;
        const int NT = N >> 4;
        int l = t & 63;
        int fi = t >> 6;
        int kc = fi / NT, nt = fi % NT;
        int k0 = kc * 32 + (l >> 4) * 8;
        int col = nt * 16 + (l & 15);
        v8bf o;
        #pragma unroll
        for (int j = 0; j < 8; ++j) o[j] = (__bf16)W[(size_t)(k0 + j) * N + col];
        *(v8bf*)(Wp + (size_t)t * 8) = o;
    } else {
        __shared__ int h[NBUCK];
        for (int i = tid; i < NBUCK; i += 256) h[i] = 0;
        __syncthreads();
        int cb = b - CVT_BLKS - 64;
        int e0 = cb * 4096;
        int e1 = e0 + 4096; if (e1 > N_EDGES) e1 = N_EDGES;
        for (int e = e0 + tid; e < e1; e += 256)
            atomicAdd(&h[clampN(dst[e]) >> 9], 1);
        __syncthreads();
        for (int i = tid; i < NBUCK; i += 256)
            if (h[i]) atomicAdd(&bucketCnt[i], h[i]);
    }
}

// ---------------- CSR build: bucketed counting sort ----------------
__global__ __launch_bounds__(256) void k_scanb(
    const int* __restrict__ bucketCnt, int* __restrict__ baseB,
    int* __restrict__ gcur, int* __restrict__ rowp)
{
    const int t = threadIdx.x;
    int v = (t < NBUCK) ? bucketCnt[t] : 0;
    int incl = v;
    #pragma unroll
    for (int off = 1; off < 64; off <<= 1) {
        int u = __shfl_up(incl, off);
        if ((t & 63) >= off) incl += u;
    }
    __shared__ int wt[4];
    if ((t & 63) == 63) wt[t >> 6] = incl;
    __syncthreads();
    int woff = 0;
    #pragma unroll
    for (int k = 0; k < 4; ++k) if (k < (t >> 6)) woff += wt[k];
    int excl = woff + incl - v;
    if (t < NBUCK) { baseB[t] = excl; gcur[t] = excl; }
    if (t == NBUCK) { baseB[NBUCK] = excl; rowp[N_NODES] = excl; }
}

__global__ __launch_bounds__(256) void k_bin(
    const int* __restrict__ src, const int* __restrict__ dst,
    int* __restrict__ gcur, unsigned int* __restrict__ packed)
{
    __shared__ unsigned int bins[256 * CAP_BIN];   // 64 KB
    __shared__ int cnt[256];
    const int tid = threadIdx.x;
    cnt[tid] = 0;
    __syncthreads();
    const int epb = (N_EDGES + gridDim.x - 1) / gridDim.x;
    int e0 = blockIdx.x * epb;
    int e1 = e0 + epb; if (e1 > N_EDGES) e1 = N_EDGES;
    for (int ch = e0; ch < e1; ch += 4096) {
        int chEnd = ch + 4096; if (chEnd > e1) chEnd = e1;
        for (int e = ch + tid; e < chEnd; e += 256) {
            int s = clampN(src[e]);
            int d = clampN(dst[e]);
            unsigned int val = (unsigned int)s | ((unsigned int)(d & 511) << 17);
            int b = d >> 9;
            int slot = atomicAdd(&cnt[b], 1);
            if (slot < CAP_BIN) bins[b * CAP_BIN + slot] = val;
            else {
                int g = atomicAdd(&gcur[b], 1);
                packed[g] = val;
            }
        }
        __syncthreads();
        int n = cnt[tid]; if (n > CAP_BIN) n = CAP_BIN;
        if (tid < NBUCK && n > 0) {
            int g = atomicAdd(&gcur[tid], n);
            for (int j = 0; j < n; ++j) packed[g + j] = bins[tid * CAP_BIN + j];
        }
        __syncthreads();
        cnt[tid] = 0;
        __syncthreads();
    }
}

__global__ __launch_bounds__(256) void k_bucket(
    const int* __restrict__ baseB, const unsigned int* __restrict__ packed,
    int* __restrict__ rowp, int* __restrict__ edge_src)
{
    __shared__ int hist[512], cur[512];
    __shared__ int wt[4];
    __shared__ unsigned int buf[CAP_B];            // 48 KB
    const int b = blockIdx.x, tid = threadIdx.x;
    const int lo = baseB[b], hi = baseB[b + 1], c = hi - lo;
    for (int i = tid; i < 512; i += 256) hist[i] = 0;
    __syncthreads();
    for (int e = tid; e < c; e += 256)
        atomicAdd(&hist[packed[lo + e] >> 17], 1);
    __syncthreads();
    int a0 = hist[2 * tid], a1 = hist[2 * tid + 1];
    int s = a0 + a1;
    int incl = s;
    #pragma unroll
    for (int off = 1; off < 64; off <<= 1) {
        int u = __shfl_up(incl, off);
        if ((tid & 63) >= off) incl += u;
    }
    if ((tid & 63) == 63) wt[tid >> 6] = incl;
    __syncthreads();
    int woff = 0;
    #pragma unroll
    for (int k = 0; k < 4; ++k) if (k < (tid >> 6)) woff += wt[k];
    int ep = woff + incl - s;
    cur[2 * tid] = ep;
    cur[2 * tid + 1] = ep + a0;
    int n0 = b * 512 + 2 * tid;
    if (n0 < N_NODES)     rowp[n0]     = lo + ep;
    if (n0 + 1 < N_NODES) rowp[n0 + 1] = lo + ep + a0;
    __syncthreads();
    for (int e = tid; e < c; e += 256) {
        unsigned int v = packed[lo + e];
        int dl = v >> 17;
        unsigned int sv = v & 0x1FFFFu;
        int pos = atomicAdd(&cur[dl], 1);
        if (pos < CAP_B) buf[pos] = sv;
        else edge_src[lo + pos] = (int)sv;
    }
    __syncthreads();
    int cc = c < CAP_B ? c : CAP_B;
    for (int e = tid; e < cc; e += 256) edge_src[lo + e] = (int)buf[e];
}

// ---------------- CSR mean-gather: one wave per node, 3-deep pipeline ----------------
// Both tables are [N][256] bf16.
// MODE 0: gather x-half (+128) of a2, write bf16 mean into agg-half (+0).
// MODE 1: gather t2-half (+0) of u2b, add own partial-half (+128), write f32 out.
template<int MODE>
__global__ __launch_bounds__(256) void k_gather16(
    const int* __restrict__ rp, const int* __restrict__ es,
    const __bf16* __restrict__ tab, void* __restrict__ outp)
{
    int wid = (blockIdx.x * 256 + threadIdx.x) >> 6;
    int l = threadIdx.x & 63;
    if (wid >= N_NODES) return;
    int start = rp[wid], end = rp[wid + 1];
    const int slot = l >> 4, c = l & 15;
    const size_t coff = (MODE == 0) ? (size_t)(128 + c * 8) : (size_t)(c * 8);
    float s0 = 0.f, s1 = 0.f, s2 = 0.f, s3 = 0.f;
    float s4 = 0.f, s5 = 0.f, s6 = 0.f, s7 = 0.f;

    int e0 = start + slot;
    int e1 = e0 + 4;
    int e2 = e1 + 4;
    bool h0 = e0 < end, h1 = e1 < end, h2 = e2 < end;
    v4u r0 = {0, 0, 0, 0}, r1 = {0, 0, 0, 0};
    if (h0) r0 = *(const v4u*)(tab + (size_t)es[e0] * 256 + coff);
    if (h1) r1 = *(const v4u*)(tab + (size_t)es[e1] * 256 + coff);
    int i2 = h2 ? es[e2] : 0;

    while (h0) {
        v4u r2 = {0, 0, 0, 0};
        if (h2) r2 = *(const v4u*)(tab + (size_t)i2 * 256 + coff);
        int e3 = e2 + 4;
        bool h3 = e3 < end;
        int i3 = h3 ? es[e3] : 0;
        s0 += bflo(r0.x); s1 += bfhi(r0.x);
        s2 += bflo(r0.y); s3 += bfhi(r0.y);
        s4 += bflo(r0.z); s5 += bfhi(r0.z);
        s6 += bflo(r0.w); s7 += bfhi(r0.w);
        r0 = r1; r1 = r2;
        h0 = h1; h1 = h2; h2 = h3;
        i2 = i3; e2 = e3;
    }

    s0 += __shfl_xor(s0, 16); s1 += __shfl_xor(s1, 16);
    s2 += __shfl_xor(s2, 16); s3 += __shfl_xor(s3, 16);
    s4 += __shfl_xor(s4, 16); s5 += __shfl_xor(s5, 16);
    s6 += __shfl_xor(s6, 16); s7 += __shfl_xor(s7, 16);
    s0 += __shfl_xor(s0, 32); s1 += __shfl_xor(s1, 32);
    s2 += __shfl_xor(s2, 32); s3 += __shfl_xor(s3, 32);
    s4 += __shfl_xor(s4, 32); s5 += __shfl_xor(s5, 32);
    s6 += __shfl_xor(s6, 32); s7 += __shfl_xor(s7, 32);
    float invd = 1.f / fmaxf((float)(end - start), 1.f);
    if (slot == 0) {
        if (MODE == 0) {
            PkU a, b, cc, d;
            a.h[0] = (__bf16)(s0 * invd); a.h[1] = (__bf16)(s1 * invd);
            b.h[0] = (__bf16)(s2 * invd); b.h[1] = (__bf16)(s3 * invd);
            cc.h[0] = (__bf16)(s4 * invd); cc.h[1] = (__bf16)(s5 * invd);
            d.h[0] = (__bf16)(s6 * invd); d.h[1] = (__bf16)(s7 * invd);
            v4u o = { a.u, b.u, cc.u, d.u };
            ((v4u*)outp)[(size_t)wid * 32 + c] = o;   // agg half of A'
        } else {
            v4u pu = *(const v4u*)(tab + (size_t)wid * 256 + 128 + c * 8);
            float4 va, vb;
            va.x = s0 * invd + bflo(pu.x); va.y = s1 * invd + bfhi(pu.x);
            va.z = s2 * invd + bflo(pu.y); va.w = s3 * invd + bfhi(pu.y);
            vb.x = s4 * invd + bflo(pu.z); vb.y = s5 * invd + bfhi(pu.z);
            vb.z = s6 * invd + bflo(pu.w); vb.w = s7 * invd + bfhi(pu.w);
            ((float4*)outp)[(size_t)wid * 32 + c * 2]     = va;
            ((float4*)outp)[(size_t)wid * 32 + c * 2 + 1] = vb;
        }
    }
}

// ---------------- weight-stationary GEMM, global_load_lds pipelined ----------------
// A staged direct-to-LDS with inverse-swizzled per-lane source (rule #21):
// LDS linear chunk (row,c16) holds global col (c16 ^ (row&7)) -> swizzled
// ds_read_b128 unchanged. Pert staged to pS the same way (linear). Both gll
// streams fly under the ds_read+MFMA phase; __syncthreads at B_h drains them.
template<int LAYER>
__device__ __forceinline__ void stage_a32(
    const __bf16* __restrict__ A, int tile, int tid, char* buf)
{
    const int row0 = tile * 32;
    #pragma unroll
    for (int k = 0; k < 2; ++k) {
        int ch = k * 512 + tid;                 // 1024 = 32 rows x 32 x 16B
        int row = ch >> 5, c16 = ch & 31;
        int sc = c16 ^ (row & 7);
        gll16(A + (size_t)(row0 + row) * 256 + sc * 8, buf + ch * 16);
    }
}

template<int LAYER>
__device__ __forceinline__ void stage_p32(
    const float* __restrict__ pert, int tile, int tid, char* pS)
{
    const int row0 = tile * 32;
    if (LAYER == 1) {
        #pragma unroll
        for (int k = 0; k < 4; ++k) {
            int ch = k * 512 + tid;             // 2048 = 32 rows x 64 x 16B
            int row = ch >> 6, c16 = ch & 63;
            gll16(pert + (size_t)(row0 + row) * 256 + c16 * 4, pS + ch * 16);
        }
    } else {
        #pragma unroll
        for (int k = 0; k < 2; ++k) {
            int ch = k * 512 + tid;             // 1024 = 32 rows x 32 x 16B
            int row = ch >> 5, c16 = ch & 31;
            gll16(pert + (size_t)(row0 + row) * 128 + c16 * 4, pS + ch * 16);
        }
    }
}

// LAYER 1: outb = h (bf16 [N][256]) = A'@[Wl1;Wr1] + bl1 + p1
// LAYER 2: outb = u2b: cols 0-127 raw t2 = h@Wl2; cols 128-255 = h@Wr2+bl2+p2
template<int LAYER>
__global__ __launch_bounds__(512, 2) void k_gws(
    const __bf16* __restrict__ A,
    const __bf16* __restrict__ WpA, const __bf16* __restrict__ WpB,
    const float* __restrict__ bias, const float* __restrict__ pert,
    __bf16* __restrict__ outb, int ntiles)
{
    __shared__ char aS0[16384];
    __shared__ char aS1[16384];
    __shared__ char hS[16384];
    __shared__ char pS[(LAYER == 1) ? 32768 : 16384];
    const int tid = threadIdx.x;
    const int w = tid >> 6, l = tid & 63;
    const int lrow = l & 15, kg = l >> 4;
    const v4f zf = {0.f, 0.f, 0.f, 0.f};

    // resident B panel (per-wave columns), identical to R10
    FragU bw[8][2];
    #pragma unroll
    for (int kc = 0; kc < 8; ++kc)
        #pragma unroll
        for (int nt = 0; nt < 2; ++nt) {
            const __bf16* Wp;
            int fi;
            if (LAYER == 1) {                // B' = [Wl1 ; Wr1] K-concat, NT=16
                Wp = (kc < 4) ? WpA : WpB;
                fi = (kc & 3) * 16 + w * 2 + nt;
            } else {                         // B'' = [Wl2 | Wr2] N-concat, NT=8
                Wp = (w < 4) ? WpA : WpB;
                fi = kc * 8 + (w & 3) * 2 + nt;
            }
            bw[kc][nt].u = *(const v4u*)(Wp + ((size_t)fi * 64 + l) * 8);
        }

    int tile = blockIdx.x;
    int cur = 0;
    if (tile < ntiles) stage_a32<LAYER>(A, tile, tid, aS0);
    __syncthreads();                         // drains prologue gll

    for (; tile < ntiles; tile += gridDim.x) {
        stage_p32<LAYER>(pert, tile, tid, pS);         // pert for THIS tile
        int nxt = tile + (int)gridDim.x;
        if (nxt < ntiles)
            stage_a32<LAYER>(A, nxt, tid, cur ? aS0 : aS1);  // A for NEXT tile
        const char* aSc = cur ? aS1 : aS0;

        const int row0 = tile * 32;
        #pragma unroll
        for (int rf = 0; rf < 2; ++rf) {
            const int arow = rf * 16 + lrow;
            FragU a[8];
            #pragma unroll
            for (int kc = 0; kc < 8; ++kc) {
                int byte = arow * 512 + ((kc * 64 + kg * 16) ^ ((arow & 7) << 4));
                a[kc].u = *(const v4u*)(aSc + byte);
            }
            v4f acc[2] = {zf, zf};
            #pragma unroll
            for (int kc = 0; kc < 8; ++kc) {
                acc[0] = __builtin_amdgcn_mfma_f32_16x16x32_bf16(a[kc].b, bw[kc][0].b, acc[0], 0, 0, 0);
                acc[1] = __builtin_amdgcn_mfma_f32_16x16x32_bf16(a[kc].b, bw[kc][1].b, acc[1], 0, 0, 0);
            }
            #pragma unroll
            for (int nt = 0; nt < 2; ++nt)
                #pragma unroll
                for (int r = 0; r < 4; ++r) {
                    int row = rf * 16 + kg * 4 + r;
                    int col = w * 32 + nt * 16 + lrow;
                    int byte = (row * 512 + col * 2) ^ ((row & 7) << 4);
                    *(__bf16*)(hS + byte) = (__bf16)acc[nt][r];
                }
        }
        __syncthreads();                      // B_h: hS visible, gll drained

        // coalesced epilogue: each wave-iter covers one full 512B row
        #pragma unroll
        for (int it = 0; it < 4; ++it) {
            int chunk = it * 512 + tid;       // 2048 = 32 rows x 64 x 8B
            int row = chunk >> 6, c4 = chunk & 63;
            int grow = row0 + row;            // N % 32 == 0: never OOB
            int byte = (row * 512 + c4 * 8) ^ ((row & 7) << 4);
            Pk2 pk; pk.u2 = *(const uint2*)(hS + byte);
            if (LAYER == 1) {
                float4 pv = *(const float4*)(pS + (row * 64 + c4) * 16);
                float4 bv = ((const float4*)bias)[c4];
                PkU o0, o1;
                o0.h[0] = (__bf16)((float)pk.h[0] + pv.x + bv.x);
                o0.h[1] = (__bf16)((float)pk.h[1] + pv.y + bv.y);
                o1.h[0] = (__bf16)((float)pk.h[2] + pv.z + bv.z);
                o1.h[1] = (__bf16)((float)pk.h[3] + pv.w + bv.w);
                uint2 ov = { o0.u, o1.u };
                *(uint2*)(outb + (size_t)grow * 256 + c4 * 4) = ov;
            } else {
                uint2 ov;
                if (c4 < 32) {
                    ov = pk.u2;               // raw t2 half
                } else {
                    float4 pv = *(const float4*)(pS + (row * 32 + (c4 - 32)) * 16);
                    float4 bv = ((const float4*)bias)[c4 - 32];
                    PkU o0, o1;
                    o0.h[0] = (__bf16)((float)pk.h[0] + pv.x + bv.x);
                    o0.h[1] = (__bf16)((float)pk.h[1] + pv.y + bv.y);
                    o1.h[0] = (__bf16)((float)pk.h[2] + pv.z + bv.z);
                    o1.h[1] = (__bf16)((float)pk.h[3] + pv.w + bv.w);
                    ov.x = o0.u; ov.y = o1.u;
                }
                *(uint2*)(outb + (size_t)grow * 256 + c4 * 4) = ov;
            }
        }
        __syncthreads();                      // B_end: hS/pS reads done
        cur ^= 1;
    }
}

extern "C" void kernel_launch(void* const* d_in, const int* in_sizes, int n_in,
                              void* d_out, int out_size, void* d_ws, size_t ws_size,
                              hipStream_t stream)
{
    const float* x   = (const float*)d_in[0];
    const int*   ei  = (const int*)d_in[1];
    const float* p1  = (const float*)d_in[2];
    const float* p2  = (const float*)d_in[3];
    const float* Wl1 = (const float*)d_in[4];
    const float* bl1 = (const float*)d_in[5];
    const float* Wr1 = (const float*)d_in[6];
    const float* Wl2 = (const float*)d_in[7];
    const float* bl2 = (const float*)d_in[8];
    const float* Wr2 = (const float*)d_in[9];
    const int* src = ei;
    const int* dst = ei + N_EDGES;

    const size_t NPAD = (size_t)N_NODES + 64;
    char* wp = (char*)d_ws;
    __bf16* a2   = (__bf16*)wp; wp += NPAD * 256 * 2;   // A' = [agg | x]
    __bf16* hb   = (__bf16*)wp; wp += NPAD * 256 * 2;   // h
    __bf16* u2b  = (__bf16*)wp; wp += NPAD * 256 * 2;   // [t2 | partial]
    __bf16* Wl1p = (__bf16*)wp; wp += 128 * 256 * 2;
    __bf16* Wr1p = (__bf16*)wp; wp += 128 * 256 * 2;
    __bf16* Wl2p = (__bf16*)wp; wp += 256 * 128 * 2;
    __bf16* Wr2p = (__bf16*)wp; wp += 256 * 128 * 2;
    int* bucketCnt = (int*)wp; wp += 512 * 4;
    int* baseB     = (int*)wp; wp += 512 * 4;
    int* gcur      = (int*)wp; wp += 512 * 4;
    int* rowp      = (int*)wp; wp += (size_t)(N_NODES + 1) * 4 + 12;
    unsigned int* packed = (unsigned int*)wp; wp += (size_t)N_EDGES * 4;
    int* es        = (int*)wp;

    hipMemsetAsync(bucketCnt, 0, 512 * 4, stream);

    const int gblocks = (N_NODES * 64 + 255) / 256;
    const int tiles32 = N_NODES / 32;                   // 3125 exact
    const int prep_blocks = CVT_BLKS + 64 + (N_EDGES + 4095) / 4096;  // 12955

    k_prep<<<prep_blocks, 256, 0, stream>>>(
        x, a2, Wl1, Wr1, Wl2, Wr2, Wl1p, Wr1p, Wl2p, Wr2p, dst, bucketCnt);
    k_scanb<<<1, 256, 0, stream>>>(bucketCnt, baseB, gcur, rowp);
    k_bin<<<256, 256, 0, stream>>>(src, dst, gcur, packed);
    k_bucket<<<NBUCK, 256, 0, stream>>>(baseB, packed, rowp, es);

    k_gather16<0><<<gblocks, 256, 0, stream>>>(rowp, es, a2, a2);
    k_gws<1><<<512, 512, 0, stream>>>(a2, Wl1p, Wr1p, bl1, p1, hb, tiles32);
    k_gws<2><<<512, 512, 0, stream>>>(hb, Wl2p, Wr2p, bl2, p2, u2b, tiles32);
    k_gather16<1><<<gblocks, 256, 0, stream>>>(rowp, es, u2b, (void*)d_out);
}